// Round 16
// baseline (111.879 us; speedup 1.0000x reference)
//
#include <hip/hip_runtime.h>
#include <hip/hip_bf16.h>
#include <math.h>

#define N_NODES 50000
#define N_EDGES 800000
#define DIM 96
#define HEADS 4
#define HEAD_DIM 24
#define SLOPE 0.2f
#define LN_EPS 1e-5f

#define CH 2048                                    // edges per sort chunk
#define NCH ((N_EDGES + CH - 1) / CH)              // 391
#define NB2 ((N_NODES + 255) / 256)                // 196 coarse buckets (dst>>8)

#define NGRP (N_NODES / 16)                        // 3125 (exact)
#define GRID_MM 784                                // transform grid
#define HLP 100                                    // transform hl row pad (f32)
#define GTP 104                                    // gtile row pad (bf16): 208B, 16B-aligned rows

typedef __attribute__((ext_vector_type(8))) short bf16x8;
typedef __attribute__((ext_vector_type(4))) float f32x4;

__device__ __forceinline__ unsigned short f2bf(float f) {
    unsigned u = __float_as_uint(f);
    u += 0x7FFFu + ((u >> 16) & 1u);          // round-to-nearest-even
    return (unsigned short)(u >> 16);
}
__device__ __forceinline__ float bf2f(unsigned short v) {
    return __uint_as_float(((unsigned)v) << 16);
}
__device__ __forceinline__ unsigned pack2bf(float a, float b) {
    return (unsigned)f2bf(a) | ((unsigned)f2bf(b) << 16);
}

// ---------------------------------------------------------------------------
// Sort pass A (+fused prep): blocks 0-8 also build bf16 B-fragments for
// W and PW^T. Then per-chunk LDS histogram over 196 coarse buckets.
// ---------------------------------------------------------------------------
__global__ __launch_bounds__(256) void k_sortA(
    const int* __restrict__ ei, int* __restrict__ cnt,
    const float* __restrict__ W, const float* __restrict__ PW,
    unsigned short* __restrict__ wfr, unsigned short* __restrict__ pwfr)
{
    const int gi = blockIdx.x * 256 + threadIdx.x;
    if (gi < 2 * 18 * 64) {                       // fused k_prep
        const int a = gi / (18 * 64);
        const int rem = gi % (18 * 64);
        const int frag = rem / 64, lane = rem % 64;
        const int fb = frag / 3, kc = frag % 3;
        const int m = lane & 15, g = lane >> 4;
        unsigned short* dst = (a ? pwfr : wfr) + (size_t)(frag * 64 + lane) * 8;
        #pragma unroll
        for (int j = 0; j < 8; ++j) {
            const int k = kc * 32 + g * 8 + j, f = fb * 16 + m;
            const float v = a ? PW[f * DIM + k] : W[k * DIM + f];   // B[k][f]
            dst[j] = f2bf(v);
        }
    }
    __shared__ int h[NB2];
    const int b = blockIdx.x, t = threadIdx.x;
    for (int k = t; k < NB2; k += 256) h[k] = 0;
    __syncthreads();
    const int e0 = b * CH;
    const int e1 = (e0 + CH < N_EDGES) ? e0 + CH : N_EDGES;
    for (int e = e0 + t; e < e1; e += 256) {
        const int d = ei[N_EDGES + e];
        if ((unsigned)d < N_NODES) atomicAdd(&h[d >> 8], 1);
    }
    __syncthreads();
    for (int k = t; k < NB2; k += 256) cnt[k * NCH + b] = h[k];
}

__global__ __launch_bounds__(512) void k_sortB1(const int* __restrict__ cnt,
                                                int* __restrict__ colpre,
                                                int* __restrict__ colsum)
{
    __shared__ int s[512];
    const int k = blockIdx.x, t = threadIdx.x;
    const int v = (t < NCH) ? cnt[k * NCH + t] : 0;
    s[t] = v;
    __syncthreads();
    #pragma unroll
    for (int off = 1; off < 512; off <<= 1) {
        const int u = (t >= off) ? s[t - off] : 0;
        __syncthreads();
        s[t] += u;
        __syncthreads();
    }
    if (t < NCH) colpre[k * NCH + t] = s[t] - v;
    if (t == 511) colsum[k] = s[511];
}

// ---------------------------------------------------------------------------
// Sort pass C: place packed (s | d_local<<16) into coarse-bucket order.
// ---------------------------------------------------------------------------
__global__ __launch_bounds__(256) void k_sortC(const int* __restrict__ ei,
                                               const int* __restrict__ colpre,
                                               const int* __restrict__ colsum,
                                               unsigned* __restrict__ staged)
{
    __shared__ int bs[256];
    __shared__ int lcur[NB2];
    const int b = blockIdx.x, t = threadIdx.x;
    const int v = (t < NB2) ? colsum[t] : 0;
    bs[t] = v;
    __syncthreads();
    #pragma unroll
    for (int off = 1; off < 256; off <<= 1) {       // inclusive scan of colsum
        const int u = (t >= off) ? bs[t - off] : 0;
        __syncthreads();
        bs[t] += u;
        __syncthreads();
    }
    if (t < NB2) lcur[t] = (bs[t] - v) + colpre[t * NCH + b];
    __syncthreads();
    const int e0 = b * CH;
    const int e1 = (e0 + CH < N_EDGES) ? e0 + CH : N_EDGES;
    for (int e = e0 + t; e < e1; e += 256) {
        int s = ei[e];
        const int d = ei[N_EDGES + e];
        if ((unsigned)d >= N_NODES) continue;
        if ((unsigned)s >= N_NODES) s = d;
        const int pos = atomicAdd(&lcur[d >> 8], 1);
        staged[pos] = (unsigned)s | ((unsigned)(d & 255) << 16);
    }
}

__global__ __launch_bounds__(512) void k_sortD(
    const unsigned* __restrict__ staged, const int* __restrict__ colsum,
    int* __restrict__ offsets, int* __restrict__ ssrc)
{
    __shared__ int bs[256];
    __shared__ int hist[256];
    __shared__ int sc[256];
    __shared__ int rs_s, re_s, tot_s;
    const int k = blockIdx.x, t = threadIdx.x;
    if (t < 256) {                                  // local scan -> bbase[k], [k+1]
        const int v = (t < NB2) ? colsum[t] : 0;
        bs[t] = v;
        __syncthreads();
        #pragma unroll
        for (int off = 1; off < 256; off <<= 1) {
            const int u = (t >= off) ? bs[t - off] : 0;
            __syncthreads();
            bs[t] += u;
            __syncthreads();
        }
        if (t == k) { rs_s = bs[t] - v; re_s = bs[t]; }
        if (t == NB2 - 1) tot_s = bs[t];
    } else {
        __syncthreads();
        #pragma unroll
        for (int off = 1; off < 256; off <<= 1) { __syncthreads(); __syncthreads(); }
    }
    __syncthreads();
    const int first = k << 8;
    const int nn = (first + 256 < N_NODES) ? 256 : N_NODES - first;
    const int rs = rs_s, re = re_s;
    if (t < 256) hist[t] = 0;
    __syncthreads();
    for (int i = rs + t; i < re; i += 512)
        atomicAdd(&hist[staged[i] >> 16], 1);
    __syncthreads();
    if (t < 256) sc[t] = hist[t];
    __syncthreads();
    #pragma unroll
    for (int off = 1; off < 256; off <<= 1) {
        int u = 0;
        if (t < 256 && t >= off) u = sc[t - off];
        __syncthreads();
        if (t < 256) sc[t] += u;
        __syncthreads();
    }
    int mycur = 0;
    if (t < 256) {
        mycur = rs + sc[t] - hist[t];
        if (t < nn) offsets[first + t] = mycur;
    }
    if (k == 0 && t == 0) offsets[N_NODES] = tot_s;
    __syncthreads();
    if (t < 256) hist[t] = mycur;
    __syncthreads();
    for (int i = rs + t; i < re; i += 512) {
        const unsigned pk = staged[i];
        const int pos = atomicAdd(&hist[pk >> 16], 1);
        ssrc[pos] = (int)(pk & 0xffffu);
    }
}

// ---------------------------------------------------------------------------
// Kernel A (MFMA): h = x @ W. One wave per 16-node group; 18 B-frags in VGPR.
// ---------------------------------------------------------------------------
__global__ __launch_bounds__(256) void k_transform(
    const float* __restrict__ x, const unsigned short* __restrict__ wfr,
    const float* __restrict__ attS, const float* __restrict__ attD,
    unsigned short* __restrict__ hb, float* __restrict__ asrc,
    float* __restrict__ adst)
{
    __shared__ float hl[4][16][HLP];          // per-wave slices, 25.6 KB
    const int tid = threadIdx.x, wv = tid >> 6, l = tid & 63;
    const int m = l & 15, g = l >> 4;

    bf16x8 wf[6][3];
    #pragma unroll
    for (int fb = 0; fb < 6; ++fb)
        #pragma unroll
        for (int kc = 0; kc < 3; ++kc)
            wf[fb][kc] = *(const bf16x8*)&wfr[(size_t)((fb * 3 + kc) * 64 + l) * 8];

    float (*h)[HLP] = hl[wv];

    for (int grp = blockIdx.x * 4 + wv; grp < NGRP; grp += gridDim.x * 4) {
        const int n0 = grp * 16;
        f32x4 acc[6];
        #pragma unroll
        for (int fb = 0; fb < 6; ++fb)
            #pragma unroll
            for (int e = 0; e < 4; ++e) acc[fb][e] = 0.f;

        #pragma unroll
        for (int kc = 0; kc < 3; ++kc) {
            const float* xp = x + (size_t)(n0 + m) * DIM + kc * 32 + g * 8;
            const float4 xa = *(const float4*)xp;
            const float4 xb = *(const float4*)(xp + 4);
            uint4 au;
            au.x = pack2bf(xa.x, xa.y); au.y = pack2bf(xa.z, xa.w);
            au.z = pack2bf(xb.x, xb.y); au.w = pack2bf(xb.z, xb.w);
            const bf16x8 af = *(const bf16x8*)&au;
            #pragma unroll
            for (int fb = 0; fb < 6; ++fb)
                acc[fb] = __builtin_amdgcn_mfma_f32_16x16x32_bf16(af, wf[fb][kc], acc[fb], 0, 0, 0);
        }
        #pragma unroll
        for (int fb = 0; fb < 6; ++fb)
            #pragma unroll
            for (int r = 0; r < 4; ++r)
                h[g * 4 + r][fb * 16 + m] = acc[fb][r];

        {   // attention dots: lane -> (node = l>>2, head = l&3)
            const int nd = l >> 2, hd = l & 3;
            const float* hr = &h[nd][hd * HEAD_DIM];
            const float* as_ = attS + hd * HEAD_DIM;
            const float* ad_ = attD + hd * HEAD_DIM;
            float s = 0.f, dd = 0.f;
            #pragma unroll
            for (int kk = 0; kk < HEAD_DIM; ++kk) {
                const float hv = hr[kk];
                s += hv * as_[kk];
                dd += hv * ad_[kk];
            }
            asrc[n0 * HEADS + l] = s;
            adst[n0 * HEADS + l] = dd;
        }
        #pragma unroll
        for (int c = l; c < 192; c += 64) {
            const int n = c / 12, q = c % 12;
            const float4 lo = *(const float4*)&h[n][q * 8];
            const float4 hi = *(const float4*)&h[n][q * 8 + 4];
            uint4 hv;
            hv.x = pack2bf(lo.x, lo.y); hv.y = pack2bf(lo.z, lo.w);
            hv.z = pack2bf(hi.x, hi.y); hv.w = pack2bf(hi.z, hi.w);
            *(uint4*)&hb[(size_t)(n0 + n) * DIM + q * 8] = hv;
        }
    }
}

// ---------------------------------------------------------------------------
// Fused aggregate + finalize. Block = 16 consecutive nodes, 4 waves x 4 nodes
// (R14 single-node pipeline per node). g rows parked in LDS bf16 tile; one
// barrier; wave 0 does proj-MFMA + residual + LayerNorm + out for all 16.
// ---------------------------------------------------------------------------
__global__ __launch_bounds__(256) void k_aggfin(
    const int* __restrict__ offsets, const int* __restrict__ ssrc,
    const unsigned short* __restrict__ hb, const float* __restrict__ asrc,
    const float* __restrict__ adst, const float* __restrict__ gb,
    const unsigned short* __restrict__ pwfr, const float* __restrict__ x,
    const float* __restrict__ pb, const float* __restrict__ lng,
    const float* __restrict__ lnb, float* __restrict__ out)
{
    __shared__ float wlds[4][256];                // per-wave 64 edges x 4 heads
    __shared__ unsigned short gtile[16][GTP];     // 16 g rows, bf16, 16B-aligned rows
    const int tid = threadIdx.x, wv = tid >> 6, lane = tid & 63;
    const int n0 = blockIdx.x * 16;
    const int lp = (lane < 48) ? lane : 47;
    const int f0 = lp * 2;
    const int hd = f0 / HEAD_DIM;
    const float gb0 = gb[f0], gb1 = gb[f0 + 1];

    for (int i = 0; i < 4; ++i) {                 // 4 nodes per wave, serial
        const int d = n0 + wv * 4 + i;
        const int rs = offsets[d], re = offsets[d + 1];
        const int deg = re - rs;
        const int sv = (lane < deg) ? ssrc[rs + lane] : d;   // coalesced preload

        {   // batch weights: lane j -> edge j
            const float4 as = *(const float4*)&asrc[sv * 4];
            const float4 ad = *(const float4*)&adst[d * 4];
            float l; float4 w;
            l = as.x + ad.x; l = (l > 0.f) ? l : SLOPE * l; w.x = __expf(l);
            l = as.y + ad.y; l = (l > 0.f) ? l : SLOPE * l; w.y = __expf(l);
            l = as.z + ad.z; l = (l > 0.f) ? l : SLOPE * l; w.z = __expf(l);
            l = as.w + ad.w; l = (l > 0.f) ? l : SLOPE * l; w.w = __expf(l);
            *(float4*)&wlds[wv][lane * 4] = w;    // wave-synchronous
        }

        float acc0, acc1, ds;
        {   // self-loop term
            const unsigned hp = *(const unsigned*)&hb[(size_t)d * DIM + f0];
            float l0 = asrc[d * HEADS + hd] + adst[d * HEADS + hd];
            l0 = (l0 > 0.f) ? l0 : SLOPE * l0;
            const float w = __expf(l0);
            acc0 = w * bf2f((unsigned short)(hp & 0xffffu));
            acc1 = w * bf2f((unsigned short)(hp >> 16));
            ds = w;
        }

#define ISSUE(hreg, wreg, j) do { \
        const int s_ = __shfl(sv, (j)); \
        hreg = *(const unsigned*)&hb[(size_t)s_ * DIM + f0]; \
        wreg = wlds[wv][(j) * 4 + hd]; } while (0)
#define CONSUME(hreg, wreg) do { \
        acc0 += (wreg) * bf2f((unsigned short)((hreg) & 0xffffu)); \
        acc1 += (wreg) * bf2f((unsigned short)((hreg) >> 16)); \
        ds += (wreg); } while (0)

        const int nd = (deg < 64) ? deg : 64;
        int j = 0;
        if (nd >= 8) {                            // 8-deep main pipeline
            unsigned p0, p1, p2, p3, p4, p5, p6, p7;
            float    q0, q1, q2, q3, q4, q5, q6, q7;
            ISSUE(p0, q0, 0); ISSUE(p1, q1, 1); ISSUE(p2, q2, 2); ISSUE(p3, q3, 3);
            ISSUE(p4, q4, 4); ISSUE(p5, q5, 5); ISSUE(p6, q6, 6); ISSUE(p7, q7, 7);
            for (; j + 16 <= nd; j += 8) {
                CONSUME(p0, q0); ISSUE(p0, q0, j + 8);
                CONSUME(p1, q1); ISSUE(p1, q1, j + 9);
                CONSUME(p2, q2); ISSUE(p2, q2, j + 10);
                CONSUME(p3, q3); ISSUE(p3, q3, j + 11);
                CONSUME(p4, q4); ISSUE(p4, q4, j + 12);
                CONSUME(p5, q5); ISSUE(p5, q5, j + 13);
                CONSUME(p6, q6); ISSUE(p6, q6, j + 14);
                CONSUME(p7, q7); ISSUE(p7, q7, j + 15);
            }
            CONSUME(p0, q0); CONSUME(p1, q1); CONSUME(p2, q2); CONSUME(p3, q3);
            CONSUME(p4, q4); CONSUME(p5, q5); CONSUME(p6, q6); CONSUME(p7, q7);
            j += 8;
        }
        if (j + 4 <= nd) {                        // 4-deep drain
            unsigned pa, pb_, pc, pd;
            float    qa, qb, qc, qd;
            ISSUE(pa, qa, j); ISSUE(pb_, qb, j + 1); ISSUE(pc, qc, j + 2); ISSUE(pd, qd, j + 3);
            CONSUME(pa, qa); CONSUME(pb_, qb); CONSUME(pc, qc); CONSUME(pd, qd);
            j += 4;
        }
        for (; j < nd; ++j) {                     // <=3 scalar tail
            unsigned hh; float ww;
            ISSUE(hh, ww, j); CONSUME(hh, ww);
        }
#undef ISSUE
#undef CONSUME
        for (j = 64; j < deg; ++j) {              // rare deg>64 fallback
            const int s_ = ssrc[rs + j];
            const unsigned hh = *(const unsigned*)&hb[(size_t)s_ * DIM + f0];
            float l_ = asrc[s_ * HEADS + hd] + adst[d * HEADS + hd];
            l_ = (l_ > 0.f) ? l_ : SLOPE * l_;
            const float w_ = __expf(l_);
            acc0 += w_ * bf2f((unsigned short)(hh & 0xffffu));
            acc1 += w_ * bf2f((unsigned short)(hh >> 16));
            ds += w_;
        }

        if (lane < 48) {
            const float inv = 1.f / ds;           // ds > 0 (self-loop)
            *(unsigned*)&gtile[wv * 4 + i][f0] =
                pack2bf(acc0 * inv + gb0, acc1 * inv + gb1);
        }
    }
    __syncthreads();
    if (wv != 0) return;

    // ---- finalize for this block's 16 nodes (wave 0 only) ----
    const int m = lane & 15, g2 = lane >> 4;
    f32x4 acc[6];
    #pragma unroll
    for (int fb = 0; fb < 6; ++fb)
        #pragma unroll
        for (int e = 0; e < 4; ++e) acc[fb][e] = 0.f;

    #pragma unroll
    for (int kc = 0; kc < 3; ++kc) {              // B-frags loaded per-kc (VGPR cap)
        const bf16x8 af = *(const bf16x8*)&gtile[m][kc * 32 + g2 * 8];
        #pragma unroll
        for (int fb = 0; fb < 6; ++fb) {
            const bf16x8 bf_ = *(const bf16x8*)&pwfr[(size_t)((fb * 3 + kc) * 64 + lane) * 8];
            acc[fb] = __builtin_amdgcn_mfma_f32_16x16x32_bf16(af, bf_, acc[fb], 0, 0, 0);
        }
    }

    float z[6][4];
    float s0 = 0.f, s1 = 0.f, s2 = 0.f, s3 = 0.f;
    float q0 = 0.f, q1 = 0.f, q2 = 0.f, q3 = 0.f;
    #pragma unroll
    for (int fb = 0; fb < 6; ++fb) {
        const float pbv = pb[fb * 16 + m];
        #pragma unroll
        for (int r = 0; r < 4; ++r) {
            const float zv = acc[fb][r] + pbv +
                x[(size_t)(n0 + g2 * 4 + r) * DIM + fb * 16 + m];
            z[fb][r] = zv;
            if (r == 0) { s0 += zv; q0 += zv * zv; }
            else if (r == 1) { s1 += zv; q1 += zv * zv; }
            else if (r == 2) { s2 += zv; q2 += zv * zv; }
            else { s3 += zv; q3 += zv * zv; }
        }
    }
    #pragma unroll
    for (int mask = 1; mask < 16; mask <<= 1) {
        s0 += __shfl_xor(s0, mask); q0 += __shfl_xor(q0, mask);
        s1 += __shfl_xor(s1, mask); q1 += __shfl_xor(q1, mask);
        s2 += __shfl_xor(s2, mask); q2 += __shfl_xor(q2, mask);
        s3 += __shfl_xor(s3, mask); q3 += __shfl_xor(q3, mask);
    }
    float mu[4], iv[4];
    mu[0] = s0 * (1.f / DIM); iv[0] = rsqrtf(q0 * (1.f / DIM) - mu[0] * mu[0] + LN_EPS);
    mu[1] = s1 * (1.f / DIM); iv[1] = rsqrtf(q1 * (1.f / DIM) - mu[1] * mu[1] + LN_EPS);
    mu[2] = s2 * (1.f / DIM); iv[2] = rsqrtf(q2 * (1.f / DIM) - mu[2] * mu[2] + LN_EPS);
    mu[3] = s3 * (1.f / DIM); iv[3] = rsqrtf(q3 * (1.f / DIM) - mu[3] * mu[3] + LN_EPS);

    #pragma unroll
    for (int fb = 0; fb < 6; ++fb) {
        const float lgv = lng[fb * 16 + m], lbv = lnb[fb * 16 + m];
        #pragma unroll
        for (int r = 0; r < 4; ++r)
            out[(size_t)(n0 + g2 * 4 + r) * DIM + fb * 16 + m] =
                lgv * (z[fb][r] - mu[r]) * iv[r] + lbv;
    }
}

// ---------------------------------------------------------------------------
extern "C" void kernel_launch(void* const* d_in, const int* in_sizes, int n_in,
                              void* d_out, int out_size, void* d_ws, size_t ws_size,
                              hipStream_t stream)
{
    const float* x    = (const float*)d_in[0];
    const int*   ei   = (const int*)d_in[1];     // [2, E] int32 (harness-converted)
    const float* W    = (const float*)d_in[2];
    const float* attS = (const float*)d_in[3];
    const float* attD = (const float*)d_in[4];
    const float* gb   = (const float*)d_in[5];
    const float* PW   = (const float*)d_in[6];
    const float* pb   = (const float*)d_in[7];
    const float* lng  = (const float*)d_in[8];
    const float* lnb  = (const float*)d_in[9];
    float* out = (float*)d_out;

    char* ws = (char*)d_ws;
    unsigned* staged = (unsigned*)ws;                             // E*4 (3.2 MB)
    float* asrc    = (float*)(staged + N_EDGES);                  // N*4
    float* adst    = asrc + N_NODES * HEADS;                      // N*4
    unsigned short* hb    = (unsigned short*)(adst + N_NODES * HEADS); // N*96 bf16
    unsigned short* wfrag = hb + (size_t)N_NODES * DIM;           // 18*64*8 bf16
    unsigned short* pwfrag= wfrag + 18 * 64 * 8;                  // 18*64*8 bf16
    int*   cnt     = (int*)(pwfrag + 18 * 64 * 8);                // NB2*NCH
    int*   colpre  = cnt + NB2 * NCH;                             // NB2*NCH
    int*   colsum  = colpre + NB2 * NCH;                          // NB2
    int*   offsets = colsum + NB2;                                // N+1
    int*   ssrc    = offsets + N_NODES + 1;                       // E

    k_sortA    <<<NCH, 256, 0, stream>>>(ei, cnt, W, PW, wfrag, pwfrag);
    k_sortB1   <<<NB2, 512, 0, stream>>>(cnt, colpre, colsum);
    k_sortC    <<<NCH, 256, 0, stream>>>(ei, colpre, colsum, staged);
    k_sortD    <<<NB2, 512, 0, stream>>>(staged, colsum, offsets, ssrc);
    k_transform<<<GRID_MM, 256, 0, stream>>>(x, wfrag, attS, attD, hb, asrc, adst);
    k_aggfin   <<<NGRP, 256, 0, stream>>>(offsets, ssrc, hb, asrc, adst, gb,
                                          pwfrag, x, pb, lng, lnb, out);
}

// Round 17
// 87.204 us; speedup vs baseline: 1.2830x; 1.2830x over previous
//
#include <hip/hip_runtime.h>
#include <hip/hip_bf16.h>
#include <math.h>

#define N_NODES 50000
#define N_EDGES 800000
#define DIM 96
#define HEADS 4
#define HEAD_DIM 24
#define SLOPE 0.2f
#define LN_EPS 1e-5f

#define CH 2048                                    // edges per sort chunk
#define NCH ((N_EDGES + CH - 1) / CH)              // 391
#define NB2 ((N_NODES + 255) / 256)                // 196 coarse buckets (dst>>8)

#define NGRP (N_NODES / 16)                        // 3125 (exact)
#define GRID_MM 784                                // 3136 waves >= 3125
#define HLP 100                                    // hl row pad (f32)

typedef __attribute__((ext_vector_type(8))) short bf16x8;
typedef __attribute__((ext_vector_type(4))) float f32x4;

__device__ __forceinline__ unsigned short f2bf(float f) {
    unsigned u = __float_as_uint(f);
    u += 0x7FFFu + ((u >> 16) & 1u);          // round-to-nearest-even
    return (unsigned short)(u >> 16);
}
__device__ __forceinline__ float bf2f(unsigned short v) {
    return __uint_as_float(((unsigned)v) << 16);
}
__device__ __forceinline__ unsigned pack2bf(float a, float b) {
    return (unsigned)f2bf(a) | ((unsigned)f2bf(b) << 16);
}

// ---------------------------------------------------------------------------
// Sort pass A (+fused prep): blocks 0-8 also build bf16 B-fragments for
// W and PW^T. Then per-chunk LDS histogram over 196 coarse buckets.
// ---------------------------------------------------------------------------
__global__ __launch_bounds__(256) void k_sortA(
    const int* __restrict__ ei, int* __restrict__ cnt,
    const float* __restrict__ W, const float* __restrict__ PW,
    unsigned short* __restrict__ wfr, unsigned short* __restrict__ pwfr)
{
    const int gi = blockIdx.x * 256 + threadIdx.x;
    if (gi < 2 * 18 * 64) {                       // fused k_prep
        const int a = gi / (18 * 64);
        const int rem = gi % (18 * 64);
        const int frag = rem / 64, lane = rem % 64;
        const int fb = frag / 3, kc = frag % 3;
        const int m = lane & 15, g = lane >> 4;
        unsigned short* dst = (a ? pwfr : wfr) + (size_t)(frag * 64 + lane) * 8;
        #pragma unroll
        for (int j = 0; j < 8; ++j) {
            const int k = kc * 32 + g * 8 + j, f = fb * 16 + m;
            const float v = a ? PW[f * DIM + k] : W[k * DIM + f];   // B[k][f]
            dst[j] = f2bf(v);
        }
    }
    __shared__ int h[NB2];
    const int b = blockIdx.x, t = threadIdx.x;
    for (int k = t; k < NB2; k += 256) h[k] = 0;
    __syncthreads();
    const int e0 = b * CH;
    const int e1 = (e0 + CH < N_EDGES) ? e0 + CH : N_EDGES;
    for (int e = e0 + t; e < e1; e += 256) {
        const int d = ei[N_EDGES + e];
        if ((unsigned)d < N_NODES) atomicAdd(&h[d >> 8], 1);
    }
    __syncthreads();
    for (int k = t; k < NB2; k += 256) cnt[k * NCH + b] = h[k];
}

__global__ __launch_bounds__(512) void k_sortB1(const int* __restrict__ cnt,
                                                int* __restrict__ colpre,
                                                int* __restrict__ colsum)
{
    __shared__ int s[512];
    const int k = blockIdx.x, t = threadIdx.x;
    const int v = (t < NCH) ? cnt[k * NCH + t] : 0;
    s[t] = v;
    __syncthreads();
    #pragma unroll
    for (int off = 1; off < 512; off <<= 1) {
        const int u = (t >= off) ? s[t - off] : 0;
        __syncthreads();
        s[t] += u;
        __syncthreads();
    }
    if (t < NCH) colpre[k * NCH + t] = s[t] - v;
    if (t == 511) colsum[k] = s[511];
}

__global__ __launch_bounds__(256) void k_sortB2(const int* __restrict__ colsum,
                                                int* __restrict__ bbase)
{
    __shared__ int s[256];
    const int t = threadIdx.x;
    const int v = (t < NB2) ? colsum[t] : 0;
    s[t] = v;
    __syncthreads();
    #pragma unroll
    for (int off = 1; off < 256; off <<= 1) {
        const int u = (t >= off) ? s[t - off] : 0;
        __syncthreads();
        s[t] += u;
        __syncthreads();
    }
    if (t < NB2) bbase[t] = s[t] - v;
    if (t == 255) bbase[NB2] = s[255];
}

// ---------------------------------------------------------------------------
// Sort pass C: place packed (s | d_local<<16) into coarse-bucket order.
// 4B per edge (s < 2^16, d_local < 2^8). LDS cursors only.
// ---------------------------------------------------------------------------
__global__ __launch_bounds__(256) void k_sortC(const int* __restrict__ ei,
                                               const int* __restrict__ colpre,
                                               const int* __restrict__ bbase,
                                               unsigned* __restrict__ staged)
{
    __shared__ int lcur[NB2];
    const int b = blockIdx.x, t = threadIdx.x;
    for (int k = t; k < NB2; k += 256) lcur[k] = bbase[k] + colpre[k * NCH + b];
    __syncthreads();
    const int e0 = b * CH;
    const int e1 = (e0 + CH < N_EDGES) ? e0 + CH : N_EDGES;
    for (int e = e0 + t; e < e1; e += 256) {
        int s = ei[e];
        const int d = ei[N_EDGES + e];
        if ((unsigned)d >= N_NODES) continue;
        if ((unsigned)s >= N_NODES) s = d;
        const int pos = atomicAdd(&lcur[d >> 8], 1);
        staged[pos] = (unsigned)s | ((unsigned)(d & 255) << 16);
    }
}

__global__ __launch_bounds__(512) void k_sortD(
    const unsigned* __restrict__ staged, const int* __restrict__ bbase,
    int* __restrict__ offsets, int* __restrict__ ssrc)
{
    __shared__ int hist[256];
    __shared__ int sc[256];
    const int k = blockIdx.x, t = threadIdx.x;
    const int first = k << 8;
    const int nn = (first + 256 < N_NODES) ? 256 : N_NODES - first;
    const int rs = bbase[k], re = bbase[k + 1];
    if (t < 256) hist[t] = 0;
    __syncthreads();
    for (int i = rs + t; i < re; i += 512)
        atomicAdd(&hist[staged[i] >> 16], 1);
    __syncthreads();
    if (t < 256) sc[t] = hist[t];
    __syncthreads();
    #pragma unroll
    for (int off = 1; off < 256; off <<= 1) {
        int u = 0;
        if (t < 256 && t >= off) u = sc[t - off];
        __syncthreads();
        if (t < 256) sc[t] += u;
        __syncthreads();
    }
    int mycur = 0;
    if (t < 256) {
        mycur = rs + sc[t] - hist[t];
        if (t < nn) offsets[first + t] = mycur;
    }
    if (k == 0 && t == 0) offsets[N_NODES] = bbase[NB2];
    __syncthreads();
    if (t < 256) hist[t] = mycur;
    __syncthreads();
    for (int i = rs + t; i < re; i += 512) {
        const unsigned pk = staged[i];
        const int pos = atomicAdd(&hist[pk >> 16], 1);
        ssrc[pos] = (int)(pk & 0xffffu);
    }
}

// ---------------------------------------------------------------------------
// Kernel A (MFMA): h = x @ W. One wave per 16-node group; 18 B-frags in VGPR.
// ---------------------------------------------------------------------------
__global__ __launch_bounds__(256) void k_transform(
    const float* __restrict__ x, const unsigned short* __restrict__ wfr,
    const float* __restrict__ attS, const float* __restrict__ attD,
    unsigned short* __restrict__ hb, float* __restrict__ asrc,
    float* __restrict__ adst)
{
    __shared__ float hl[4][16][HLP];          // per-wave slices, 25.6 KB
    const int tid = threadIdx.x, wv = tid >> 6, l = tid & 63;
    const int m = l & 15, g = l >> 4;

    bf16x8 wf[6][3];
    #pragma unroll
    for (int fb = 0; fb < 6; ++fb)
        #pragma unroll
        for (int kc = 0; kc < 3; ++kc)
            wf[fb][kc] = *(const bf16x8*)&wfr[(size_t)((fb * 3 + kc) * 64 + l) * 8];

    float (*h)[HLP] = hl[wv];

    for (int grp = blockIdx.x * 4 + wv; grp < NGRP; grp += gridDim.x * 4) {
        const int n0 = grp * 16;
        f32x4 acc[6];
        #pragma unroll
        for (int fb = 0; fb < 6; ++fb)
            #pragma unroll
            for (int e = 0; e < 4; ++e) acc[fb][e] = 0.f;

        #pragma unroll
        for (int kc = 0; kc < 3; ++kc) {
            const float* xp = x + (size_t)(n0 + m) * DIM + kc * 32 + g * 8;
            const float4 xa = *(const float4*)xp;
            const float4 xb = *(const float4*)(xp + 4);
            uint4 au;
            au.x = pack2bf(xa.x, xa.y); au.y = pack2bf(xa.z, xa.w);
            au.z = pack2bf(xb.x, xb.y); au.w = pack2bf(xb.z, xb.w);
            const bf16x8 af = *(const bf16x8*)&au;
            #pragma unroll
            for (int fb = 0; fb < 6; ++fb)
                acc[fb] = __builtin_amdgcn_mfma_f32_16x16x32_bf16(af, wf[fb][kc], acc[fb], 0, 0, 0);
        }
        #pragma unroll
        for (int fb = 0; fb < 6; ++fb)
            #pragma unroll
            for (int r = 0; r < 4; ++r)
                h[g * 4 + r][fb * 16 + m] = acc[fb][r];

        {   // attention dots: lane -> (node = l>>2, head = l&3)
            const int nd = l >> 2, hd = l & 3;
            const float* hr = &h[nd][hd * HEAD_DIM];
            const float* as_ = attS + hd * HEAD_DIM;
            const float* ad_ = attD + hd * HEAD_DIM;
            float s = 0.f, dd = 0.f;
            #pragma unroll
            for (int kk = 0; kk < HEAD_DIM; ++kk) {
                const float hv = hr[kk];
                s += hv * as_[kk];
                dd += hv * ad_[kk];
            }
            asrc[n0 * HEADS + l] = s;
            adst[n0 * HEADS + l] = dd;
        }
        #pragma unroll
        for (int c = l; c < 192; c += 64) {
            const int n = c / 12, q = c % 12;
            const float4 lo = *(const float4*)&h[n][q * 8];
            const float4 hi = *(const float4*)&h[n][q * 8 + 4];
            uint4 hv;
            hv.x = pack2bf(lo.x, lo.y); hv.y = pack2bf(lo.z, lo.w);
            hv.z = pack2bf(hi.x, hi.y); hv.w = pack2bf(hi.z, hi.w);
            *(uint4*)&hb[(size_t)(n0 + n) * DIM + q * 8] = hv;
        }
    }
}

// ---------------------------------------------------------------------------
// Kernel C: gather-aggregate. Batch weight phase: lane j computes edge j's
// 4 head-weights (one float4 asrc gather + 4 exps per <=64 edges), parks in
// per-wave LDS; h-loop reads w via conflict-free ds_read. 8-deep h pipeline.
// ---------------------------------------------------------------------------
__global__ __launch_bounds__(256) void k_aggregate(
    const int* __restrict__ offsets, const int* __restrict__ ssrc,
    const unsigned short* __restrict__ hb, const float* __restrict__ asrc,
    const float* __restrict__ adst, const float* __restrict__ gb,
    unsigned short* __restrict__ gbuf)
{
    __shared__ float wlds[4][256];               // per-wave 64 edges x 4 heads
    const int wid  = (blockIdx.x * 256 + threadIdx.x) >> 6;
    const int lane = threadIdx.x & 63;
    if (wid >= N_NODES) return;
    const int wv = (threadIdx.x >> 6) & 3;
    const int d = wid;
    const int lp = (lane < 48) ? lane : 47;      // lanes 48-63 duplicate lane 47
    const int f0 = lp * 2;                       // features f0, f0+1 (same head)
    const int hd = f0 / HEAD_DIM;

    const int rs = offsets[d], re = offsets[d + 1];
    const int deg = re - rs;
    const int sv = (lane < deg) ? ssrc[rs + lane] : d;   // coalesced preload

    {   // batch weights: lane j -> edge j (valid dummy for j >= deg)
        const float4 as = *(const float4*)&asrc[sv * 4];
        const float4 ad = *(const float4*)&adst[d * 4];
        float l; float4 w;
        l = as.x + ad.x; l = (l > 0.f) ? l : SLOPE * l; w.x = __expf(l);
        l = as.y + ad.y; l = (l > 0.f) ? l : SLOPE * l; w.y = __expf(l);
        l = as.z + ad.z; l = (l > 0.f) ? l : SLOPE * l; w.z = __expf(l);
        l = as.w + ad.w; l = (l > 0.f) ? l : SLOPE * l; w.w = __expf(l);
        *(float4*)&wlds[wv][lane * 4] = w;       // wave-synchronous, no barrier
    }

    float acc0, acc1, ds;
    {   // self-loop term
        const unsigned hp = *(const unsigned*)&hb[(size_t)d * DIM + f0];
        float l0 = asrc[d * HEADS + hd] + adst[d * HEADS + hd];
        l0 = (l0 > 0.f) ? l0 : SLOPE * l0;
        const float w = __expf(l0);
        acc0 = w * bf2f((unsigned short)(hp & 0xffffu));
        acc1 = w * bf2f((unsigned short)(hp >> 16));
        ds = w;
    }

#define ISSUE(hreg, wreg, j) do { \
        const int s_ = __shfl(sv, (j)); \
        hreg = *(const unsigned*)&hb[(size_t)s_ * DIM + f0]; \
        wreg = wlds[wv][(j) * 4 + hd]; } while (0)
#define CONSUME(hreg, wreg) do { \
        acc0 += (wreg) * bf2f((unsigned short)((hreg) & 0xffffu)); \
        acc1 += (wreg) * bf2f((unsigned short)((hreg) >> 16)); \
        ds += (wreg); } while (0)

    const int nd = (deg < 64) ? deg : 64;
    int j = 0;
    if (nd >= 8) {                               // 8-deep main pipeline
        unsigned p0, p1, p2, p3, p4, p5, p6, p7;
        float    q0, q1, q2, q3, q4, q5, q6, q7;
        ISSUE(p0, q0, 0); ISSUE(p1, q1, 1); ISSUE(p2, q2, 2); ISSUE(p3, q3, 3);
        ISSUE(p4, q4, 4); ISSUE(p5, q5, 5); ISSUE(p6, q6, 6); ISSUE(p7, q7, 7);
        for (; j + 16 <= nd; j += 8) {
            CONSUME(p0, q0); ISSUE(p0, q0, j + 8);
            CONSUME(p1, q1); ISSUE(p1, q1, j + 9);
            CONSUME(p2, q2); ISSUE(p2, q2, j + 10);
            CONSUME(p3, q3); ISSUE(p3, q3, j + 11);
            CONSUME(p4, q4); ISSUE(p4, q4, j + 12);
            CONSUME(p5, q5); ISSUE(p5, q5, j + 13);
            CONSUME(p6, q6); ISSUE(p6, q6, j + 14);
            CONSUME(p7, q7); ISSUE(p7, q7, j + 15);
        }
        CONSUME(p0, q0); CONSUME(p1, q1); CONSUME(p2, q2); CONSUME(p3, q3);
        CONSUME(p4, q4); CONSUME(p5, q5); CONSUME(p6, q6); CONSUME(p7, q7);
        j += 8;
    }
    if (j + 4 <= nd) {                           // 4-deep drain
        unsigned pa, pb_, pc, pd;
        float    qa, qb, qc, qd;
        ISSUE(pa, qa, j); ISSUE(pb_, qb, j + 1); ISSUE(pc, qc, j + 2); ISSUE(pd, qd, j + 3);
        CONSUME(pa, qa); CONSUME(pb_, qb); CONSUME(pc, qc); CONSUME(pd, qd);
        j += 4;
    }
    for (; j < nd; ++j) {                        // <=3 scalar tail
        unsigned hh; float ww;
        ISSUE(hh, ww, j); CONSUME(hh, ww);
    }
#undef ISSUE
#undef CONSUME
    for (j = 64; j < deg; ++j) {                 // rare deg>64: inline weights
        const int s_ = ssrc[rs + j];
        const unsigned hh = *(const unsigned*)&hb[(size_t)s_ * DIM + f0];
        float l_ = asrc[s_ * HEADS + hd] + adst[d * HEADS + hd];
        l_ = (l_ > 0.f) ? l_ : SLOPE * l_;
        const float w_ = __expf(l_);
        acc0 += w_ * bf2f((unsigned short)(hh & 0xffffu));
        acc1 += w_ * bf2f((unsigned short)(hh >> 16));
        ds += w_;
    }

    if (lane < 48) {
        const float inv = 1.f / ds;              // ds > 0 (self-loop)
        const float o0 = acc0 * inv + gb[f0];
        const float o1 = acc1 * inv + gb[f0 + 1];
        *(unsigned*)&gbuf[(size_t)d * DIM + f0] = pack2bf(o0, o1);
    }
}

// ---------------------------------------------------------------------------
// Kernel D (MFMA): proj = g @ PW^T + pb, + residual + LayerNorm, in-register.
// ---------------------------------------------------------------------------
__global__ __launch_bounds__(256) void k_finalize(
    const float* __restrict__ x, const unsigned short* __restrict__ pwfr,
    const float* __restrict__ pb, const float* __restrict__ lng,
    const float* __restrict__ lnb, const unsigned short* __restrict__ gbuf,
    float* __restrict__ out)
{
    const int tid = threadIdx.x, wv = tid >> 6, l = tid & 63;
    const int m = l & 15, g = l >> 4;

    bf16x8 wf[6][3];
    #pragma unroll
    for (int fb = 0; fb < 6; ++fb)
        #pragma unroll
        for (int kc = 0; kc < 3; ++kc)
            wf[fb][kc] = *(const bf16x8*)&pwfr[(size_t)((fb * 3 + kc) * 64 + l) * 8];

    float pbv[6], lgv[6], lbv[6];
    #pragma unroll
    for (int fb = 0; fb < 6; ++fb) {
        pbv[fb] = pb[fb * 16 + m];
        lgv[fb] = lng[fb * 16 + m];
        lbv[fb] = lnb[fb * 16 + m];
    }

    for (int grp = blockIdx.x * 4 + wv; grp < NGRP; grp += gridDim.x * 4) {
        const int n0 = grp * 16;
        f32x4 acc[6];
        #pragma unroll
        for (int fb = 0; fb < 6; ++fb)
            #pragma unroll
            for (int e = 0; e < 4; ++e) acc[fb][e] = 0.f;

        #pragma unroll
        for (int kc = 0; kc < 3; ++kc) {
            const bf16x8 af = *(const bf16x8*)&gbuf[(size_t)(n0 + m) * DIM + kc * 32 + g * 8];
            #pragma unroll
            for (int fb = 0; fb < 6; ++fb)
                acc[fb] = __builtin_amdgcn_mfma_f32_16x16x32_bf16(af, wf[fb][kc], acc[fb], 0, 0, 0);
        }

        float z[6][4];
        float s0 = 0.f, s1 = 0.f, s2 = 0.f, s3 = 0.f;
        float q0 = 0.f, q1 = 0.f, q2 = 0.f, q3 = 0.f;
        #pragma unroll
        for (int fb = 0; fb < 6; ++fb) {
            #pragma unroll
            for (int r = 0; r < 4; ++r) {
                const float zv = acc[fb][r] + pbv[fb] +
                    x[(size_t)(n0 + g * 4 + r) * DIM + fb * 16 + m];
                z[fb][r] = zv;
                if (r == 0) { s0 += zv; q0 += zv * zv; }
                else if (r == 1) { s1 += zv; q1 += zv * zv; }
                else if (r == 2) { s2 += zv; q2 += zv * zv; }
                else { s3 += zv; q3 += zv * zv; }
            }
        }
        #pragma unroll
        for (int mask = 1; mask < 16; mask <<= 1) {
            s0 += __shfl_xor(s0, mask); q0 += __shfl_xor(q0, mask);
            s1 += __shfl_xor(s1, mask); q1 += __shfl_xor(q1, mask);
            s2 += __shfl_xor(s2, mask); q2 += __shfl_xor(q2, mask);
            s3 += __shfl_xor(s3, mask); q3 += __shfl_xor(q3, mask);
        }
        float mu[4], iv[4];
        mu[0] = s0 * (1.f / DIM); iv[0] = rsqrtf(q0 * (1.f / DIM) - mu[0] * mu[0] + LN_EPS);
        mu[1] = s1 * (1.f / DIM); iv[1] = rsqrtf(q1 * (1.f / DIM) - mu[1] * mu[1] + LN_EPS);
        mu[2] = s2 * (1.f / DIM); iv[2] = rsqrtf(q2 * (1.f / DIM) - mu[2] * mu[2] + LN_EPS);
        mu[3] = s3 * (1.f / DIM); iv[3] = rsqrtf(q3 * (1.f / DIM) - mu[3] * mu[3] + LN_EPS);

        #pragma unroll
        for (int fb = 0; fb < 6; ++fb)
            #pragma unroll
            for (int r = 0; r < 4; ++r)
                out[(size_t)(n0 + g * 4 + r) * DIM + fb * 16 + m] =
                    lgv[fb] * (z[fb][r] - mu[r]) * iv[r] + lbv[fb];
    }
}

// ---------------------------------------------------------------------------
extern "C" void kernel_launch(void* const* d_in, const int* in_sizes, int n_in,
                              void* d_out, int out_size, void* d_ws, size_t ws_size,
                              hipStream_t stream)
{
    const float* x    = (const float*)d_in[0];
    const int*   ei   = (const int*)d_in[1];     // [2, E] int32 (harness-converted)
    const float* W    = (const float*)d_in[2];
    const float* attS = (const float*)d_in[3];
    const float* attD = (const float*)d_in[4];
    const float* gb   = (const float*)d_in[5];
    const float* PW   = (const float*)d_in[6];
    const float* pb   = (const float*)d_in[7];
    const float* lng  = (const float*)d_in[8];
    const float* lnb  = (const float*)d_in[9];
    float* out = (float*)d_out;

    char* ws = (char*)d_ws;
    unsigned* staged = (unsigned*)ws;                             // E*4 (3.2 MB)
    float* asrc    = (float*)(staged + N_EDGES);                  // N*4
    float* adst    = asrc + N_NODES * HEADS;                      // N*4
    unsigned short* hb    = (unsigned short*)(adst + N_NODES * HEADS); // N*96 bf16
    unsigned short* gbuf  = hb + (size_t)N_NODES * DIM;           // N*96 bf16
    unsigned short* wfrag = gbuf + (size_t)N_NODES * DIM;         // 18*64*8 bf16
    unsigned short* pwfrag= wfrag + 18 * 64 * 8;                  // 18*64*8 bf16
    int*   cnt     = (int*)(pwfrag + 18 * 64 * 8);                // NB2*NCH
    int*   colpre  = cnt + NB2 * NCH;                             // NB2*NCH
    int*   colsum  = colpre + NB2 * NCH;                          // NB2
    int*   bbase   = colsum + NB2;                                // NB2+1
    int*   offsets = bbase + NB2 + 1;                             // N+1
    int*   ssrc    = offsets + N_NODES + 1;                       // E

    k_sortA    <<<NCH, 256, 0, stream>>>(ei, cnt, W, PW, wfrag, pwfrag);
    k_sortB1   <<<NB2, 512, 0, stream>>>(cnt, colpre, colsum);
    k_sortB2   <<<1, 256, 0, stream>>>(colsum, bbase);
    k_sortC    <<<NCH, 256, 0, stream>>>(ei, colpre, bbase, staged);
    k_sortD    <<<NB2, 512, 0, stream>>>(staged, bbase, offsets, ssrc);
    k_transform<<<GRID_MM, 256, 0, stream>>>(x, wfrag, attS, attD, hb, asrc, adst);
    k_aggregate<<<(N_NODES * 64 + 255) / 256, 256, 0, stream>>>(offsets, ssrc, hb, asrc, adst, gb, gbuf);
    k_finalize <<<GRID_MM, 256, 0, stream>>>(x, pwfrag, pb, lng, lnb, gbuf, out);
}